// Round 6
// baseline (356.014 us; speedup 1.0000x reference)
//
#include <hip/hip_runtime.h>
#include <math.h>

#define L_LEN  3072
#define CH512  512
#define TOPK   40
#define NBATCH 8
#define TWSZ   1088            // 1024 twiddles + swizzle pad (ph = j + (j>>4), max 1086)
#define SW(i)  ((i) + ((i) >> 5))   // LDS bank-conflict swizzle for re/im
#define FFTSZ  3168            // SW(3071) = 3166 -> round up

// ---------------------------------------------------------------------------
// In-LDS 3072-point complex FFT: N = 3 x 1024, radix-4 (fused radix-2 pairs)
// + radix-3 combine. re/im are SW-swizzled arrays of FFTSZ floats.
// Input must be placed at SW(r*1024 + brev10(m)) for x[3m+r].
// Twiddles: Ctab/Stab[j + (j>>4)] = cos/sin(2*pi*j/3072), j in [0,1024).
// sgn = -1 forward, +1 inverse (unnormalized). Output natural order (SW'd).
// Caller must __syncthreads() after writing re/im before calling.
// ---------------------------------------------------------------------------
__device__ __forceinline__ void fft3072(float* re, float* im,
                                        const float* Ctab, const float* Stab,
                                        int tid, float sgn)
{
    // 5 fused double-stages: s = 0,2,4,6,8 on the three 1024-subarrays
    #pragma unroll
    for (int s = 0; s < 10; s += 2) {
        int q = 1 << s;
        #pragma unroll
        for (int ii = 0; ii < 3; ii++) {
            int ib  = tid + (ii << 8);          // 0..767 butterflies
            int sub = ib >> 8;
            int t   = ib & 255;
            int pos = t & (q - 1);
            int base= t >> s;
            int i0  = (sub << 10) + (base << (s + 2)) + pos;
            int p0 = SW(i0), p1 = SW(i0 + q), p2 = SW(i0 + 2*q), p3 = SW(i0 + 3*q);
            int j2 = 3 * (pos << (8 - s));      // T2 angle index (2*pi*j2/3072)
            int ph = j2 + (j2 >> 4);
            float c2 = Ctab[ph], s2 = sgn * Stab[ph];
            float c1 = c2*c2 - s2*s2, s1 = 2.0f*c2*s2;     // T1 = T2^2
            float a0r = re[p0], a0i = im[p0];
            float a1r = re[p1], a1i = im[p1];
            float a2r = re[p2], a2i = im[p2];
            float a3r = re[p3], a3i = im[p3];
            // stage s: pairs (0,1) and (2,3), twiddle T1
            float t1r = c1*a1r - s1*a1i, t1i = c1*a1i + s1*a1r;
            float u0r = a0r + t1r, u0i = a0i + t1i;
            float u1r = a0r - t1r, u1i = a0i - t1i;
            float t3r = c1*a3r - s1*a3i, t3i = c1*a3i + s1*a3r;
            float u2r = a2r + t3r, u2i = a2i + t3i;
            float u3r = a2r - t3r, u3i = a2i - t3i;
            // stage s+1: pairs (0,2) twiddle T2; (1,3) twiddle sgn*i*T2
            float w2r = c2*u2r - s2*u2i, w2i = c2*u2i + s2*u2r;
            float w3r = c2*u3r - s2*u3i, w3i = c2*u3i + s2*u3r;
            float iw3r = -sgn * w3i, iw3i = sgn * w3r;
            re[p0] = u0r + w2r;  im[p0] = u0i + w2i;
            re[p2] = u0r - w2r;  im[p2] = u0i - w2i;
            re[p1] = u1r + iw3r; im[p1] = u1i + iw3i;
            re[p3] = u1r - iw3r; im[p3] = u1i - iw3i;
        }
        __syncthreads();
    }
    // radix-3 combine: X[k+1024j] from Y0,Y1,Y2
    #pragma unroll
    for (int ii = 0; ii < 4; ii++) {
        int kk = tid + (ii << 8);               // 0..1023
        int ph = kk + (kk >> 4);
        float c1 = Ctab[ph];
        float s1 = sgn * Stab[ph];
        float c2 = c1*c1 - s1*s1;               // W2 = W1^2
        float s2 = 2.0f*c1*s1;
        int pk0 = SW(kk), pk1 = SW(1024 + kk), pk2 = SW(2048 + kk);
        float y0r = re[pk0], y0i = im[pk0];
        float y1r = re[pk1], y1i = im[pk1];
        float y2r = re[pk2], y2i = im[pk2];
        float t1r = c1*y1r - s1*y1i, t1i = c1*y1i + s1*y1r;
        float t2r = c2*y2r - s2*y2i, t2i = c2*y2i + s2*y2r;
        float ur = t1r + t2r, ui = t1i + t2i;
        float vr = t1r - t2r, vi = t1i - t2i;
        float mr = y0r - 0.5f*ur, mi = y0i - 0.5f*ui;
        float s3 = sgn * 0.86602540378443864676f;
        re[pk0] = y0r + ur;      im[pk0] = y0i + ui;
        re[pk1] = mr - s3*vi;    im[pk1] = mi + s3*vr;
        re[pk2] = mr + s3*vi;    im[pk2] = mi - s3*vr;
    }
    __syncthreads();
}

__device__ __forceinline__ void fill_twiddles(float* Ctab, float* Stab, int tid)
{
    const float TWO_PI = 6.28318530717958647692f;
    for (int j = tid; j < 1024; j += 256) {
        float ang = TWO_PI * (float)j / 3072.0f;
        float c, s;
        __sincosf(ang, &s, &c);
        int ph = j + (j >> 4);
        Ctab[ph] = c; Stab[ph] = s;
    }
}

// ---------------------------------------------------------------------------
// Transpose kernel: [B, L, C] -> [B, C, L] for q and k. 64x64 tiles, float4
// loads and stores (256 B contiguous per 16 lanes). blockIdx.z = b*2 + which.
// ---------------------------------------------------------------------------
__global__ __launch_bounds__(256) void transpose_kernel(
    const float* __restrict__ q, const float* __restrict__ k,
    float* __restrict__ qT, float* __restrict__ kT)
{
    __shared__ float tile[64][65];
    int which = blockIdx.z & 1;
    int b     = blockIdx.z >> 1;
    int l0    = blockIdx.x << 6;
    int c0    = blockIdx.y << 6;
    int x4 = threadIdx.x & 15;          // float4 column
    int y  = threadIdx.x >> 4;          // 0..15
    const float* src = which ? k : q;
    float* dst       = which ? kT : qT;
    size_t in_base = (size_t)b * L_LEN * CH512;
    #pragma unroll
    for (int p = 0; p < 4; p++) {
        int r = y + (p << 4);
        float4 v = *(const float4*)(src + in_base + (size_t)(l0 + r) * CH512 + c0 + (x4 << 2));
        tile[r][(x4 << 2) + 0] = v.x;
        tile[r][(x4 << 2) + 1] = v.y;
        tile[r][(x4 << 2) + 2] = v.z;
        tile[r][(x4 << 2) + 3] = v.w;
    }
    __syncthreads();
    size_t out_base = (size_t)b * CH512 * L_LEN;
    #pragma unroll
    for (int p = 0; p < 4; p++) {
        int c = y + (p << 4);
        float4 w;
        w.x = tile[(x4 << 2) + 0][c];
        w.y = tile[(x4 << 2) + 1][c];
        w.z = tile[(x4 << 2) + 2][c];
        w.w = tile[(x4 << 2) + 3][c];
        *(float4*)(dst + out_base + (size_t)(c0 + c) * L_LEN + l0 + (x4 << 2)) = w;
    }
}

// ---------------------------------------------------------------------------
// Kernel A: per (b, channel-QUAD): packed FFT z = q + i*k per channel,
// extract P = Q*conj(K) via Hermitian split, accumulate 4 channels in
// REGISTERS (12 re + 12 im per thread), one atomicAdd pass into S[b].
// Inputs transposed [B, C, L]. LDS ~34 KB -> 4 blocks/CU.
// XCD swizzle (r5): default dispatch spreads a batch's 128 blocks over all
// 8 XCDs -> the shared S[b] atomic region ping-pongs between L2s (measured:
// FETCH 138 MB vs 100 ideal, WRITE 70 vs 25). Remap so each XCD owns one
// batch: atomics stay in local L2.
// Register prefetch (r5): next channel's 6 float4 loads issue right after
// the deposit, so HBM latency hides under the 6-barrier FFT phase (T14).
// ---------------------------------------------------------------------------
__global__ __launch_bounds__(256, 4) void corr_fft_kernel(
    const float* __restrict__ qT, const float* __restrict__ kT,
    float* __restrict__ S_re, float* __restrict__ S_im)
{
    __shared__ float re[FFTSZ], im[FFTSZ];
    __shared__ float Ctab[TWSZ], Stab[TWSZ];
    int pid = blockIdx.x;
    int blk = ((pid & 7) << 7) + (pid >> 3);   // XCD-colocating bijection (1024%8==0)
    int b   = blk >> 7;            // == pid & 7: one batch per XCD
    int c0  = (blk & 127) << 2;    // channel quad base
    int tid = threadIdx.x;

    fill_twiddles(Ctab, Stab, tid);

    float accR[12], accI[12];
    #pragma unroll
    for (int it = 0; it < 12; it++) { accR[it] = 0.0f; accI[it] = 0.0f; }

    // prefetch channel 0
    float4 rq0, rq1, rq2, rk0, rk1, rk2;
    {
        size_t ch_off = ((size_t)b * CH512 + c0) * L_LEN;
        const float4* q4 = (const float4*)(qT + ch_off);
        const float4* k4 = (const float4*)(kT + ch_off);
        rq0 = q4[tid]; rq1 = q4[tid + 256]; rq2 = q4[tid + 512];
        rk0 = k4[tid]; rk1 = k4[tid + 256]; rk2 = k4[tid + 512];
    }

    #pragma unroll
    for (int ec = 0; ec < 4; ec++) {
        __syncthreads();   // re/im free (covers table fill on ec==0, extract otherwise)
        // deposit current channel from registers
        #pragma unroll
        for (int it = 0; it < 3; it++) {
            int idx = tid + (it << 8);
            float4 xq = (it == 0) ? rq0 : (it == 1) ? rq1 : rq2;
            float4 xk = (it == 0) ? rk0 : (it == 1) ? rk1 : rk2;
            #pragma unroll
            for (int j = 0; j < 4; j++) {
                int n = (idx << 2) + j;
                int m = n / 3;
                int r = n - 3 * m;
                int dst = SW((r << 10) + (__brev((unsigned)m) >> 22));
                float qv = (j == 0) ? xq.x : (j == 1) ? xq.y : (j == 2) ? xq.z : xq.w;
                float kv = (j == 0) ? xk.x : (j == 1) ? xk.y : (j == 2) ? xk.z : xk.w;
                re[dst] = qv;
                im[dst] = kv;
            }
        }
        // issue next channel's loads now; they complete during the FFT barriers
        if (ec < 3) {
            size_t ch_off = ((size_t)b * CH512 + c0 + ec + 1) * L_LEN;
            const float4* q4 = (const float4*)(qT + ch_off);
            const float4* k4 = (const float4*)(kT + ch_off);
            rq0 = q4[tid]; rq1 = q4[tid + 256]; rq2 = q4[tid + 512];
            rk0 = k4[tid]; rk1 = k4[tid + 256]; rk2 = k4[tid + 512];
        }
        __syncthreads();
        fft3072(re, im, Ctab, Stab, tid, -1.0f);
        // P = (i/4) * (A+B) * conj(A-B),  A = Z[f], B = conj(Z[(N-f)%N])
        #pragma unroll
        for (int it = 0; it < 12; it++) {
            int f = tid + (it << 8);
            int g = (f == 0) ? 0 : (L_LEN - f);
            int pf = SW(f), pg = SW(g);
            float ar = re[pf], ai = im[pf];
            float br = re[pg], bi = -im[pg];
            float ur = ar + br, ui = ai + bi;
            float vr = ar - br, vi = ai - bi;
            accR[it] += 0.25f * (ur * vi - ui * vr);
            accI[it] += 0.25f * (ur * vr + ui * vi);
        }
    }
    #pragma unroll
    for (int it = 0; it < 12; it++) {
        int f = tid + (it << 8);
        atomicAdd(&S_re[b * L_LEN + f], accR[it]);
        atomicAdd(&S_im[b * L_LEN + f], accI[it]);
    }
}

// ---------------------------------------------------------------------------
// Fused kernel B+C: inverse FFT of S[b] -> values -> EXACT top-40 via 48-bit
// composite radix-select (value desc, index asc; all composites distinct so
// tie-break is structural) -> rank-sort 40 -> softmax -> wts[b]; block 0
// writes shifts.
// Composite: c = (ordkey(val) << 12) | (4095 - idx), 44 bits used.
// ---------------------------------------------------------------------------
__global__ __launch_bounds__(256) void ifft_topk_kernel(
    const float* __restrict__ S_re, const float* __restrict__ S_im,
    float* __restrict__ wts, int* __restrict__ shifts)
{
    __shared__ float re[FFTSZ], im[FFTSZ];
    __shared__ float Ctab[TWSZ], Stab[TWSZ];
    __shared__ unsigned hist[256];
    __shared__ unsigned long long s_pref;
    __shared__ unsigned s_need;
    __shared__ unsigned s_cnt;
    __shared__ unsigned selk[TOPK];
    __shared__ unsigned selidx[TOPK];
    __shared__ float sv[TOPK];
    __shared__ int   si[TOPK];

    int b = blockIdx.x;
    int tid = threadIdx.x;
    fill_twiddles(Ctab, Stab, tid);
    #pragma unroll
    for (int it = 0; it < 12; it++) {
        int n = tid + (it << 8);
        int m = n / 3;
        int r = n - 3 * m;
        int dst = SW((r << 10) + (__brev((unsigned)m) >> 22));
        re[dst] = S_re[b * L_LEN + n];
        im[dst] = S_im[b * L_LEN + n];
    }
    __syncthreads();
    fft3072(re, im, Ctab, Stab, tid, 1.0f);

    // keys: monotone uint mapping of scaled values, stored linearly in im space
    unsigned* key = (unsigned*)im;      // im no longer needed (imag part discarded)
    const float scale = 1.0f / (3072.0f * 512.0f);
    #pragma unroll
    for (int it = 0; it < 12; it++) {
        int t = tid + (it << 8);
        float v = re[SW(t)] * scale;
        unsigned u = __float_as_uint(v);
        key[t] = (u & 0x80000000u) ? ~u : (u | 0x80000000u);
    }
    if (tid == 0) { s_pref = 0ULL; s_need = TOPK; s_cnt = 0u; }
    __syncthreads();

    // 6 x 8-bit radix passes over the 48-bit composite (bits 47..0; top 4 zero)
    #pragma unroll
    for (int p = 5; p >= 0; --p) {
        hist[tid] = 0u;                 // blockDim == 256 == bins
        __syncthreads();
        unsigned long long pref = s_pref;
        unsigned need = s_need;
        #pragma unroll
        for (int it = 0; it < 12; it++) {
            int t = tid + (it << 8);
            unsigned long long c = ((unsigned long long)key[t] << 12) | (unsigned)(4095 - t);
            if ((c >> ((p + 1) * 8)) == (pref >> ((p + 1) * 8)))
                atomicAdd(&hist[(unsigned)((c >> (p * 8)) & 0xFFu)], 1u);
        }
        __syncthreads();
        if (tid < 64) {
            int l = tid;
            unsigned s0 = hist[4*l] + hist[4*l+1] + hist[4*l+2] + hist[4*l+3];
            unsigned T = s0;            // inclusive suffix sum over lane chunks
            #pragma unroll
            for (int off = 1; off < 64; off <<= 1) {
                unsigned o = __shfl_down(T, off);
                if (l + off < 64) T += o;
            }
            unsigned above = T - s0;    // count in chunks strictly above l
            if (T >= need && above < need) {   // unique crossing lane
                unsigned acc = above;
                int bin = -1;
                #pragma unroll
                for (int j = 3; j >= 0; --j) {
                    unsigned h = hist[4*l + j];
                    if (bin < 0) {
                        if (acc + h >= need) bin = 4*l + j;
                        else acc += h;
                    }
                }
                s_pref = pref | ((unsigned long long)(unsigned)bin << (p * 8));
                s_need = need - acc;
            }
        }
        __syncthreads();
    }

    // collect exactly TOPK elements with composite >= threshold
    unsigned long long cstar = s_pref;
    #pragma unroll
    for (int it = 0; it < 12; it++) {
        int t = tid + (it << 8);
        unsigned long long c = ((unsigned long long)key[t] << 12) | (unsigned)(4095 - t);
        if (c >= cstar) {
            unsigned pos = atomicAdd(&s_cnt, 1u);
            if (pos < TOPK) { selk[pos] = key[t]; selidx[pos] = (unsigned)t; }
        }
    }
    __syncthreads();

    // rank-sort the 40 (desc by composite -> value desc, index asc)
    if (tid < TOPK) {
        unsigned mk = selk[tid], mi = selidx[tid];
        unsigned long long mc = ((unsigned long long)mk << 12) | (unsigned)(4095 - mi);
        int rank = 0;
        #pragma unroll
        for (int j = 0; j < TOPK; j++) {
            unsigned long long cj = ((unsigned long long)selk[j] << 12) | (unsigned)(4095 - selidx[j]);
            rank += (cj > mc) ? 1 : 0;
        }
        unsigned u = (mk & 0x80000000u) ? (mk ^ 0x80000000u) : ~mk;  // inverse ordkey
        sv[rank] = __uint_as_float(u);
        si[rank] = (int)mi;
    }
    __syncthreads();

    if (tid == 0) {
        float mx = sv[0];
        float sum = 0.0f;
        float ex[TOPK];
        for (int kk = 0; kk < TOPK; kk++) { ex[kk] = __expf(sv[kk] - mx); sum += ex[kk]; }
        float inv = 1.0f / sum;
        for (int kk = 0; kk < TOPK; kk++) wts[b * TOPK + kk] = ex[kk] * inv;
        if (b == 0)
            for (int kk = 0; kk < TOPK; kk++) shifts[kk] = si[kk];
    }
}

// ---------------------------------------------------------------------------
// Kernel D: out[b,t,ch] = sum_k w[b,k] * v[b,(t+s_k)%L,ch]
// LDS-gather: block = (b, 4-channel group); stage the entire L=3072 column
// (48 KB) into LDS once, gather 40 taps from LDS (ds_read_b128, lane-linear
// = conflict-free). XCD-colocating swizzle keeps the 4 sibling cg-blocks
// sharing each 64 B line on one XCD L2 (r4->r5: FETCH 197->~60 MB).
// ---------------------------------------------------------------------------
__global__ __launch_bounds__(512) void agg_kernel(
    const float* __restrict__ v, const float* __restrict__ wts,
    const int* __restrict__ shifts, float* __restrict__ out)
{
    __shared__ float4 vcol[L_LEN];      // 48 KB: [row][4ch]
    __shared__ float w[TOPK];
    __shared__ int   sh[TOPK];
    int pid = blockIdx.x;
    int idx = ((pid & 7) << 7) + (pid >> 3);   // XCD-colocating bijection
    int cg  = idx & 127;                // channel group (4 ch)
    int b   = idx >> 7;
    int tid = threadIdx.x;
    int ch  = cg << 2;
    if (tid < TOPK) { w[tid] = wts[b * TOPK + tid]; sh[tid] = shifts[tid]; }
    size_t vbase = (size_t)b * L_LEN * CH512 + ch;
    // stage: 6 rows per thread (lane-consecutive rows, 16 B each)
    #pragma unroll
    for (int it = 0; it < 6; it++) {
        int r = tid + (it << 9);
        vcol[r] = *(const float4*)(v + vbase + (size_t)r * CH512);
    }
    __syncthreads();
    // gather: 6 output rows per thread, taps outer for ILP (6 indep ds_reads)
    float4 acc0 = make_float4(0.f,0.f,0.f,0.f);
    float4 acc1 = acc0, acc2 = acc0, acc3 = acc0, acc4 = acc0, acc5 = acc0;
    #pragma unroll 8
    for (int kk = 0; kk < TOPK; kk++) {
        float ww = w[kk];
        int s = sh[kk];
        int t0 = tid + s;            if (t0 >= L_LEN) t0 -= L_LEN;
        int t1 = tid + 512 + s;      if (t1 >= L_LEN) t1 -= L_LEN;
        int t2 = tid + 1024 + s;     if (t2 >= L_LEN) t2 -= L_LEN;
        int t3 = tid + 1536 + s;     if (t3 >= L_LEN) t3 -= L_LEN;
        int t4 = tid + 2048 + s;     if (t4 >= L_LEN) t4 -= L_LEN;
        int t5 = tid + 2560 + s;     if (t5 >= L_LEN) t5 -= L_LEN;
        float4 x0 = vcol[t0], x1 = vcol[t1], x2 = vcol[t2];
        float4 x3 = vcol[t3], x4 = vcol[t4], x5 = vcol[t5];
        acc0.x += x0.x*ww; acc0.y += x0.y*ww; acc0.z += x0.z*ww; acc0.w += x0.w*ww;
        acc1.x += x1.x*ww; acc1.y += x1.y*ww; acc1.z += x1.z*ww; acc1.w += x1.w*ww;
        acc2.x += x2.x*ww; acc2.y += x2.y*ww; acc2.z += x2.z*ww; acc2.w += x2.w*ww;
        acc3.x += x3.x*ww; acc3.y += x3.y*ww; acc3.z += x3.z*ww; acc3.w += x3.w*ww;
        acc4.x += x4.x*ww; acc4.y += x4.y*ww; acc4.z += x4.z*ww; acc4.w += x4.w*ww;
        acc5.x += x5.x*ww; acc5.y += x5.y*ww; acc5.z += x5.z*ww; acc5.w += x5.w*ww;
    }
    *(float4*)(out + vbase + (size_t)(tid         ) * CH512) = acc0;
    *(float4*)(out + vbase + (size_t)(tid + 512   ) * CH512) = acc1;
    *(float4*)(out + vbase + (size_t)(tid + 1024  ) * CH512) = acc2;
    *(float4*)(out + vbase + (size_t)(tid + 1536  ) * CH512) = acc3;
    *(float4*)(out + vbase + (size_t)(tid + 2048  ) * CH512) = acc4;
    *(float4*)(out + vbase + (size_t)(tid + 2560  ) * CH512) = acc5;
}

// ---------------------------------------------------------------------------
extern "C" void kernel_launch(void* const* d_in, const int* in_sizes, int n_in,
                              void* d_out, int out_size, void* d_ws, size_t ws_size,
                              hipStream_t stream)
{
    const float* q = (const float*)d_in[0];
    const float* k = (const float*)d_in[1];
    const float* v = (const float*)d_in[2];
    float* out = (float*)d_out;
    float* ws  = (float*)d_ws;

    const size_t TSZ = (size_t)NBATCH * CH512 * L_LEN;   // 12.58M floats

    // qT uses d_out as scratch (agg overwrites it last); kT + small bufs in ws.
    float* qT = out;
    float* kT = ws;
    float* S_re = ws + TSZ;                              // 8*3072
    float* S_im = S_re + NBATCH * L_LEN;                 // 8*3072
    float* wts  = S_im + NBATCH * L_LEN;                 // 8*40
    int*   shifts = (int*)(wts + NBATCH * TOPK);         // 40

    hipMemsetAsync(S_re, 0, (size_t)2 * NBATCH * L_LEN * sizeof(float), stream);

    transpose_kernel<<<dim3(L_LEN / 64, CH512 / 64, NBATCH * 2), dim3(256), 0, stream>>>(
        q, k, qT, kT);
    // 8 batches x 128 channel-quads = 1024 blocks -> 4 blocks/CU (LDS limit)
    corr_fft_kernel<<<dim3(1024), dim3(256), 0, stream>>>(qT, kT, S_re, S_im);
    ifft_topk_kernel<<<dim3(NBATCH), dim3(256), 0, stream>>>(S_re, S_im, wts, shifts);
    // 8 b x 128 channel-quads = 1024 blocks, 512 threads, 48 KB LDS
    agg_kernel<<<dim3(NBATCH * (CH512 / 4)), dim3(512), 0, stream>>>(v, wts, shifts, out);
}

// Round 7
// 294.479 us; speedup vs baseline: 1.2090x; 1.2090x over previous
//
#include <hip/hip_runtime.h>
#include <math.h>

#define L_LEN  3072
#define CH512  512
#define TOPK   40
#define NBATCH 8
#define TWSZ   1088            // 1024 twiddles + pad (ph = j + (j>>4), max 1086)
#define SW(i)  ((i) + ((i) >> 5))   // scalar-float LDS swizzle (ifft_topk)
#define FFTSZ  3168            // SW(3071) = 3166 -> round up
#define SW2(i) ((i) + ((i) >> 4))   // float2 LDS swizzle (128 B = 16 elems/bank-row)
#define FFTSZ2 3264            // SW2(3071) = 3262 -> round up

typedef __attribute__((ext_vector_type(2))) float f32x2;

// ---------------------------------------------------------------------------
// Scalar in-LDS 3072-point complex FFT (used by ifft_topk): N = 3 x 1024,
// radix-4 (fused radix-2 pairs) + radix-3 combine. SW-swizzled arrays.
// Input at SW(r*1024 + brev10(m)) for x[3m+r]. sgn=-1 fwd, +1 inv (unnorm).
// ---------------------------------------------------------------------------
__device__ __forceinline__ void fft3072(float* re, float* im,
                                        const float* Ctab, const float* Stab,
                                        int tid, float sgn)
{
    #pragma unroll
    for (int s = 0; s < 10; s += 2) {
        int q = 1 << s;
        #pragma unroll
        for (int ii = 0; ii < 3; ii++) {
            int ib  = tid + (ii << 8);
            int sub = ib >> 8;
            int t   = ib & 255;
            int pos = t & (q - 1);
            int base= t >> s;
            int i0  = (sub << 10) + (base << (s + 2)) + pos;
            int p0 = SW(i0), p1 = SW(i0 + q), p2 = SW(i0 + 2*q), p3 = SW(i0 + 3*q);
            int j2 = 3 * (pos << (8 - s));
            int ph = j2 + (j2 >> 4);
            float c2 = Ctab[ph], s2 = sgn * Stab[ph];
            float c1 = c2*c2 - s2*s2, s1 = 2.0f*c2*s2;
            float a0r = re[p0], a0i = im[p0];
            float a1r = re[p1], a1i = im[p1];
            float a2r = re[p2], a2i = im[p2];
            float a3r = re[p3], a3i = im[p3];
            float t1r = c1*a1r - s1*a1i, t1i = c1*a1i + s1*a1r;
            float u0r = a0r + t1r, u0i = a0i + t1i;
            float u1r = a0r - t1r, u1i = a0i - t1i;
            float t3r = c1*a3r - s1*a3i, t3i = c1*a3i + s1*a3r;
            float u2r = a2r + t3r, u2i = a2i + t3i;
            float u3r = a2r - t3r, u3i = a2i - t3i;
            float w2r = c2*u2r - s2*u2i, w2i = c2*u2i + s2*u2r;
            float w3r = c2*u3r - s2*u3i, w3i = c2*u3i + s2*u3r;
            float iw3r = -sgn * w3i, iw3i = sgn * w3r;
            re[p0] = u0r + w2r;  im[p0] = u0i + w2i;
            re[p2] = u0r - w2r;  im[p2] = u0i - w2i;
            re[p1] = u1r + iw3r; im[p1] = u1i + iw3i;
            re[p3] = u1r - iw3r; im[p3] = u1i - iw3i;
        }
        __syncthreads();
    }
    #pragma unroll
    for (int ii = 0; ii < 4; ii++) {
        int kk = tid + (ii << 8);
        int ph = kk + (kk >> 4);
        float c1 = Ctab[ph];
        float s1 = sgn * Stab[ph];
        float c2 = c1*c1 - s1*s1;
        float s2 = 2.0f*c1*s1;
        int pk0 = SW(kk), pk1 = SW(1024 + kk), pk2 = SW(2048 + kk);
        float y0r = re[pk0], y0i = im[pk0];
        float y1r = re[pk1], y1i = im[pk1];
        float y2r = re[pk2], y2i = im[pk2];
        float t1r = c1*y1r - s1*y1i, t1i = c1*y1i + s1*y1r;
        float t2r = c2*y2r - s2*y2i, t2i = c2*y2i + s2*y2r;
        float ur = t1r + t2r, ui = t1i + t2i;
        float vr = t1r - t2r, vi = t1i - t2i;
        float mr = y0r - 0.5f*ur, mi = y0i - 0.5f*ui;
        float s3 = sgn * 0.86602540378443864676f;
        re[pk0] = y0r + ur;      im[pk0] = y0i + ui;
        re[pk1] = mr - s3*vi;    im[pk1] = mi + s3*vr;
        re[pk2] = mr + s3*vi;    im[pk2] = mi - s3*vr;
    }
    __syncthreads();
}

// ---------------------------------------------------------------------------
// Packed 2-channel FFT: identical structure, f32x2 data lanes (ch a in [0],
// ch b in [1]), scalar twiddles broadcast. SW2 swizzle (b64-balanced: every
// stage stride gives 4 bank-accesses/bank/wave = structural minimum).
// Halves LDS instruction count per block vs 4 scalar FFTs -> attacks the
// measured LDS-throughput bound (~56 us of r5-corr's 84).
// ---------------------------------------------------------------------------
__device__ __forceinline__ void fft3072p(f32x2* re, f32x2* im,
                                         const float* Ctab, const float* Stab,
                                         int tid, float sgn)
{
    #pragma unroll
    for (int s = 0; s < 10; s += 2) {
        int q = 1 << s;
        #pragma unroll
        for (int ii = 0; ii < 3; ii++) {
            int ib  = tid + (ii << 8);
            int sub = ib >> 8;
            int t   = ib & 255;
            int pos = t & (q - 1);
            int base= t >> s;
            int i0  = (sub << 10) + (base << (s + 2)) + pos;
            int p0 = SW2(i0), p1 = SW2(i0 + q), p2 = SW2(i0 + 2*q), p3 = SW2(i0 + 3*q);
            int j2 = 3 * (pos << (8 - s));
            int ph = j2 + (j2 >> 4);
            float c2 = Ctab[ph], s2 = sgn * Stab[ph];
            float c1 = c2*c2 - s2*s2, s1 = 2.0f*c2*s2;
            f32x2 a0r = re[p0], a0i = im[p0];
            f32x2 a1r = re[p1], a1i = im[p1];
            f32x2 a2r = re[p2], a2i = im[p2];
            f32x2 a3r = re[p3], a3i = im[p3];
            f32x2 t1r = c1*a1r - s1*a1i, t1i = c1*a1i + s1*a1r;
            f32x2 u0r = a0r + t1r, u0i = a0i + t1i;
            f32x2 u1r = a0r - t1r, u1i = a0i - t1i;
            f32x2 t3r = c1*a3r - s1*a3i, t3i = c1*a3i + s1*a3r;
            f32x2 u2r = a2r + t3r, u2i = a2i + t3i;
            f32x2 u3r = a2r - t3r, u3i = a2i - t3i;
            f32x2 w2r = c2*u2r - s2*u2i, w2i = c2*u2i + s2*u2r;
            f32x2 w3r = c2*u3r - s2*u3i, w3i = c2*u3i + s2*u3r;
            f32x2 iw3r = (-sgn) * w3i, iw3i = sgn * w3r;
            re[p0] = u0r + w2r;  im[p0] = u0i + w2i;
            re[p2] = u0r - w2r;  im[p2] = u0i - w2i;
            re[p1] = u1r + iw3r; im[p1] = u1i + iw3i;
            re[p3] = u1r - iw3r; im[p3] = u1i - iw3i;
        }
        __syncthreads();
    }
    #pragma unroll
    for (int ii = 0; ii < 4; ii++) {
        int kk = tid + (ii << 8);
        int ph = kk + (kk >> 4);
        float c1 = Ctab[ph];
        float s1 = sgn * Stab[ph];
        float c2 = c1*c1 - s1*s1;
        float s2 = 2.0f*c1*s1;
        int pk0 = SW2(kk), pk1 = SW2(1024 + kk), pk2 = SW2(2048 + kk);
        f32x2 y0r = re[pk0], y0i = im[pk0];
        f32x2 y1r = re[pk1], y1i = im[pk1];
        f32x2 y2r = re[pk2], y2i = im[pk2];
        f32x2 t1r = c1*y1r - s1*y1i, t1i = c1*y1i + s1*y1r;
        f32x2 t2r = c2*y2r - s2*y2i, t2i = c2*y2i + s2*y2r;
        f32x2 ur = t1r + t2r, ui = t1i + t2i;
        f32x2 vr = t1r - t2r, vi = t1i - t2i;
        f32x2 mr = y0r - 0.5f*ur, mi = y0i - 0.5f*ui;
        float s3 = sgn * 0.86602540378443864676f;
        re[pk0] = y0r + ur;      im[pk0] = y0i + ui;
        re[pk1] = mr - s3*vi;    im[pk1] = mi + s3*vr;
        re[pk2] = mr + s3*vi;    im[pk2] = mi - s3*vr;
    }
    __syncthreads();
}

__device__ __forceinline__ void fill_twiddles(float* Ctab, float* Stab, int tid)
{
    const float TWO_PI = 6.28318530717958647692f;
    for (int j = tid; j < 1024; j += 256) {
        float ang = TWO_PI * (float)j / 3072.0f;
        float c, s;
        __sincosf(ang, &s, &c);
        int ph = j + (j >> 4);
        Ctab[ph] = c; Stab[ph] = s;
    }
}

// ---------------------------------------------------------------------------
// Transpose kernel: [B, L, C] -> [B, C, L] for q and k. 64x64 tiles, float4
// loads and stores (256 B contiguous per 16 lanes). blockIdx.z = b*2 + which.
// ---------------------------------------------------------------------------
__global__ __launch_bounds__(256) void transpose_kernel(
    const float* __restrict__ q, const float* __restrict__ k,
    float* __restrict__ qT, float* __restrict__ kT)
{
    __shared__ float tile[64][65];
    int which = blockIdx.z & 1;
    int b     = blockIdx.z >> 1;
    int l0    = blockIdx.x << 6;
    int c0    = blockIdx.y << 6;
    int x4 = threadIdx.x & 15;
    int y  = threadIdx.x >> 4;
    const float* src = which ? k : q;
    float* dst       = which ? kT : qT;
    size_t in_base = (size_t)b * L_LEN * CH512;
    #pragma unroll
    for (int p = 0; p < 4; p++) {
        int r = y + (p << 4);
        float4 v = *(const float4*)(src + in_base + (size_t)(l0 + r) * CH512 + c0 + (x4 << 2));
        tile[r][(x4 << 2) + 0] = v.x;
        tile[r][(x4 << 2) + 1] = v.y;
        tile[r][(x4 << 2) + 2] = v.z;
        tile[r][(x4 << 2) + 3] = v.w;
    }
    __syncthreads();
    size_t out_base = (size_t)b * CH512 * L_LEN;
    #pragma unroll
    for (int p = 0; p < 4; p++) {
        int c = y + (p << 4);
        float4 w;
        w.x = tile[(x4 << 2) + 0][c];
        w.y = tile[(x4 << 2) + 1][c];
        w.z = tile[(x4 << 2) + 2][c];
        w.w = tile[(x4 << 2) + 3][c];
        *(float4*)(dst + out_base + (size_t)(c0 + c) * L_LEN + l0 + (x4 << 2)) = w;
    }
}

// ---------------------------------------------------------------------------
// Kernel A: per (b, channel-QUAD), processed as TWO float2-packed pair-FFTs.
// z = q + i*k per channel; P = Q*conj(K) via Hermitian split; accumulate all
// 4 channels in 12+12 scalar registers; one atomicAdd pass into S[b].
// r6 lessons reverted: no register prefetch (spilled to scratch: WRITE
// 70->182 MB), no XCD swizzle (atomics are placement-independent).
// LDS 60.9 KB -> 2 blocks/CU; launch_bounds(256,2) = 256-VGPR cap, no spill.
// ---------------------------------------------------------------------------
__global__ __launch_bounds__(256, 2) void corr_fft_kernel(
    const float* __restrict__ qT, const float* __restrict__ kT,
    float* __restrict__ S_re, float* __restrict__ S_im)
{
    __shared__ f32x2 re2[FFTSZ2], im2[FFTSZ2];
    __shared__ float Ctab[TWSZ], Stab[TWSZ];
    int blk = blockIdx.x;
    int b   = blk >> 7;            // 128 quads per batch
    int c0  = (blk & 127) << 2;    // channel quad base
    int tid = threadIdx.x;

    fill_twiddles(Ctab, Stab, tid);

    float accR[12], accI[12];
    #pragma unroll
    for (int it = 0; it < 12; it++) { accR[it] = 0.0f; accI[it] = 0.0f; }

    for (int pp = 0; pp < 2; pp++) {
        int ca = c0 + (pp << 1);
        const float4* qa4 = (const float4*)(qT + ((size_t)b * CH512 + ca) * L_LEN);
        const float4* qb4 = (const float4*)(qT + ((size_t)b * CH512 + ca + 1) * L_LEN);
        const float4* ka4 = (const float4*)(kT + ((size_t)b * CH512 + ca) * L_LEN);
        const float4* kb4 = (const float4*)(kT + ((size_t)b * CH512 + ca + 1) * L_LEN);
        __syncthreads();   // re2/im2 free (covers table fill on pp==0, extract otherwise)
        #pragma unroll
        for (int it = 0; it < 3; it++) {
            int idx = tid + (it << 8);
            float4 xqa = qa4[idx], xqb = qb4[idx];
            float4 xka = ka4[idx], xkb = kb4[idx];
            #pragma unroll
            for (int j = 0; j < 4; j++) {
                int n = (idx << 2) + j;
                int m = n / 3;
                int r = n - 3 * m;
                int dst = SW2((r << 10) + (__brev((unsigned)m) >> 22));
                float qav = (j == 0) ? xqa.x : (j == 1) ? xqa.y : (j == 2) ? xqa.z : xqa.w;
                float qbv = (j == 0) ? xqb.x : (j == 1) ? xqb.y : (j == 2) ? xqb.z : xqb.w;
                float kav = (j == 0) ? xka.x : (j == 1) ? xka.y : (j == 2) ? xka.z : xka.w;
                float kbv = (j == 0) ? xkb.x : (j == 1) ? xkb.y : (j == 2) ? xkb.z : xkb.w;
                f32x2 vr = {qav, qbv};
                f32x2 vi = {kav, kbv};
                re2[dst] = vr;
                im2[dst] = vi;
            }
        }
        __syncthreads();
        fft3072p(re2, im2, Ctab, Stab, tid, -1.0f);
        // P = (i/4) * (A+B) * conj(A-B),  A = Z[f], B = conj(Z[(N-f)%N])
        #pragma unroll
        for (int it = 0; it < 12; it++) {
            int f = tid + (it << 8);
            int g = (f == 0) ? 0 : (L_LEN - f);
            int pf = SW2(f), pg = SW2(g);
            f32x2 ar = re2[pf], ai = im2[pf];
            f32x2 br = re2[pg], bi = -im2[pg];
            f32x2 ur = ar + br, ui = ai + bi;
            f32x2 vr = ar - br, vi = ai - bi;
            f32x2 pr = 0.25f * (ur * vi - ui * vr);
            f32x2 pi = 0.25f * (ur * vr + ui * vi);
            accR[it] += pr[0] + pr[1];
            accI[it] += pi[0] + pi[1];
        }
    }
    #pragma unroll
    for (int it = 0; it < 12; it++) {
        int f = tid + (it << 8);
        atomicAdd(&S_re[b * L_LEN + f], accR[it]);
        atomicAdd(&S_im[b * L_LEN + f], accI[it]);
    }
}

// ---------------------------------------------------------------------------
// Fused kernel B+C: inverse FFT of S[b] -> values -> EXACT top-40 via 48-bit
// composite radix-select (value desc, index asc) -> rank-sort 40 -> softmax
// -> wts[b]; block 0 writes shifts.
// ---------------------------------------------------------------------------
__global__ __launch_bounds__(256) void ifft_topk_kernel(
    const float* __restrict__ S_re, const float* __restrict__ S_im,
    float* __restrict__ wts, int* __restrict__ shifts)
{
    __shared__ float re[FFTSZ], im[FFTSZ];
    __shared__ float Ctab[TWSZ], Stab[TWSZ];
    __shared__ unsigned hist[256];
    __shared__ unsigned long long s_pref;
    __shared__ unsigned s_need;
    __shared__ unsigned s_cnt;
    __shared__ unsigned selk[TOPK];
    __shared__ unsigned selidx[TOPK];
    __shared__ float sv[TOPK];
    __shared__ int   si[TOPK];

    int b = blockIdx.x;
    int tid = threadIdx.x;
    fill_twiddles(Ctab, Stab, tid);
    #pragma unroll
    for (int it = 0; it < 12; it++) {
        int n = tid + (it << 8);
        int m = n / 3;
        int r = n - 3 * m;
        int dst = SW((r << 10) + (__brev((unsigned)m) >> 22));
        re[dst] = S_re[b * L_LEN + n];
        im[dst] = S_im[b * L_LEN + n];
    }
    __syncthreads();
    fft3072(re, im, Ctab, Stab, tid, 1.0f);

    unsigned* key = (unsigned*)im;
    const float scale = 1.0f / (3072.0f * 512.0f);
    #pragma unroll
    for (int it = 0; it < 12; it++) {
        int t = tid + (it << 8);
        float v = re[SW(t)] * scale;
        unsigned u = __float_as_uint(v);
        key[t] = (u & 0x80000000u) ? ~u : (u | 0x80000000u);
    }
    if (tid == 0) { s_pref = 0ULL; s_need = TOPK; s_cnt = 0u; }
    __syncthreads();

    #pragma unroll
    for (int p = 5; p >= 0; --p) {
        hist[tid] = 0u;
        __syncthreads();
        unsigned long long pref = s_pref;
        unsigned need = s_need;
        #pragma unroll
        for (int it = 0; it < 12; it++) {
            int t = tid + (it << 8);
            unsigned long long c = ((unsigned long long)key[t] << 12) | (unsigned)(4095 - t);
            if ((c >> ((p + 1) * 8)) == (pref >> ((p + 1) * 8)))
                atomicAdd(&hist[(unsigned)((c >> (p * 8)) & 0xFFu)], 1u);
        }
        __syncthreads();
        if (tid < 64) {
            int l = tid;
            unsigned s0 = hist[4*l] + hist[4*l+1] + hist[4*l+2] + hist[4*l+3];
            unsigned T = s0;
            #pragma unroll
            for (int off = 1; off < 64; off <<= 1) {
                unsigned o = __shfl_down(T, off);
                if (l + off < 64) T += o;
            }
            unsigned above = T - s0;
            if (T >= need && above < need) {
                unsigned acc = above;
                int bin = -1;
                #pragma unroll
                for (int j = 3; j >= 0; --j) {
                    unsigned h = hist[4*l + j];
                    if (bin < 0) {
                        if (acc + h >= need) bin = 4*l + j;
                        else acc += h;
                    }
                }
                s_pref = pref | ((unsigned long long)(unsigned)bin << (p * 8));
                s_need = need - acc;
            }
        }
        __syncthreads();
    }

    unsigned long long cstar = s_pref;
    #pragma unroll
    for (int it = 0; it < 12; it++) {
        int t = tid + (it << 8);
        unsigned long long c = ((unsigned long long)key[t] << 12) | (unsigned)(4095 - t);
        if (c >= cstar) {
            unsigned pos = atomicAdd(&s_cnt, 1u);
            if (pos < TOPK) { selk[pos] = key[t]; selidx[pos] = (unsigned)t; }
        }
    }
    __syncthreads();

    if (tid < TOPK) {
        unsigned mk = selk[tid], mi = selidx[tid];
        unsigned long long mc = ((unsigned long long)mk << 12) | (unsigned)(4095 - mi);
        int rank = 0;
        #pragma unroll
        for (int j = 0; j < TOPK; j++) {
            unsigned long long cj = ((unsigned long long)selk[j] << 12) | (unsigned)(4095 - selidx[j]);
            rank += (cj > mc) ? 1 : 0;
        }
        unsigned u = (mk & 0x80000000u) ? (mk ^ 0x80000000u) : ~mk;
        sv[rank] = __uint_as_float(u);
        si[rank] = (int)mi;
    }
    __syncthreads();

    if (tid == 0) {
        float mx = sv[0];
        float sum = 0.0f;
        float ex[TOPK];
        for (int kk = 0; kk < TOPK; kk++) { ex[kk] = __expf(sv[kk] - mx); sum += ex[kk]; }
        float inv = 1.0f / sum;
        for (int kk = 0; kk < TOPK; kk++) wts[b * TOPK + kk] = ex[kk] * inv;
        if (b == 0)
            for (int kk = 0; kk < TOPK; kk++) shifts[kk] = si[kk];
    }
}

// ---------------------------------------------------------------------------
// Kernel D: out[b,t,ch] = sum_k w[b,k] * v[b,(t+s_k)%L,ch]
// LDS-gather + XCD-colocating swizzle (proven r4->r5: sibling cg-blocks
// sharing each 64 B line land on one XCD L2).
// ---------------------------------------------------------------------------
__global__ __launch_bounds__(512) void agg_kernel(
    const float* __restrict__ v, const float* __restrict__ wts,
    const int* __restrict__ shifts, float* __restrict__ out)
{
    __shared__ float4 vcol[L_LEN];      // 48 KB: [row][4ch]
    __shared__ float w[TOPK];
    __shared__ int   sh[TOPK];
    int pid = blockIdx.x;
    int idx = ((pid & 7) << 7) + (pid >> 3);   // XCD-colocating bijection
    int cg  = idx & 127;
    int b   = idx >> 7;
    int tid = threadIdx.x;
    int ch  = cg << 2;
    if (tid < TOPK) { w[tid] = wts[b * TOPK + tid]; sh[tid] = shifts[tid]; }
    size_t vbase = (size_t)b * L_LEN * CH512 + ch;
    #pragma unroll
    for (int it = 0; it < 6; it++) {
        int r = tid + (it << 9);
        vcol[r] = *(const float4*)(v + vbase + (size_t)r * CH512);
    }
    __syncthreads();
    float4 acc0 = make_float4(0.f,0.f,0.f,0.f);
    float4 acc1 = acc0, acc2 = acc0, acc3 = acc0, acc4 = acc0, acc5 = acc0;
    #pragma unroll 8
    for (int kk = 0; kk < TOPK; kk++) {
        float ww = w[kk];
        int s = sh[kk];
        int t0 = tid + s;            if (t0 >= L_LEN) t0 -= L_LEN;
        int t1 = tid + 512 + s;      if (t1 >= L_LEN) t1 -= L_LEN;
        int t2 = tid + 1024 + s;     if (t2 >= L_LEN) t2 -= L_LEN;
        int t3 = tid + 1536 + s;     if (t3 >= L_LEN) t3 -= L_LEN;
        int t4 = tid + 2048 + s;     if (t4 >= L_LEN) t4 -= L_LEN;
        int t5 = tid + 2560 + s;     if (t5 >= L_LEN) t5 -= L_LEN;
        float4 x0 = vcol[t0], x1 = vcol[t1], x2 = vcol[t2];
        float4 x3 = vcol[t3], x4 = vcol[t4], x5 = vcol[t5];
        acc0.x += x0.x*ww; acc0.y += x0.y*ww; acc0.z += x0.z*ww; acc0.w += x0.w*ww;
        acc1.x += x1.x*ww; acc1.y += x1.y*ww; acc1.z += x1.z*ww; acc1.w += x1.w*ww;
        acc2.x += x2.x*ww; acc2.y += x2.y*ww; acc2.z += x2.z*ww; acc2.w += x2.w*ww;
        acc3.x += x3.x*ww; acc3.y += x3.y*ww; acc3.z += x3.z*ww; acc3.w += x3.w*ww;
        acc4.x += x4.x*ww; acc4.y += x4.y*ww; acc4.z += x4.z*ww; acc4.w += x4.w*ww;
        acc5.x += x5.x*ww; acc5.y += x5.y*ww; acc5.z += x5.z*ww; acc5.w += x5.w*ww;
    }
    *(float4*)(out + vbase + (size_t)(tid         ) * CH512) = acc0;
    *(float4*)(out + vbase + (size_t)(tid + 512   ) * CH512) = acc1;
    *(float4*)(out + vbase + (size_t)(tid + 1024  ) * CH512) = acc2;
    *(float4*)(out + vbase + (size_t)(tid + 1536  ) * CH512) = acc3;
    *(float4*)(out + vbase + (size_t)(tid + 2048  ) * CH512) = acc4;
    *(float4*)(out + vbase + (size_t)(tid + 2560  ) * CH512) = acc5;
}

// ---------------------------------------------------------------------------
extern "C" void kernel_launch(void* const* d_in, const int* in_sizes, int n_in,
                              void* d_out, int out_size, void* d_ws, size_t ws_size,
                              hipStream_t stream)
{
    const float* q = (const float*)d_in[0];
    const float* k = (const float*)d_in[1];
    const float* v = (const float*)d_in[2];
    float* out = (float*)d_out;
    float* ws  = (float*)d_ws;

    const size_t TSZ = (size_t)NBATCH * CH512 * L_LEN;   // 12.58M floats

    float* qT = out;
    float* kT = ws;
    float* S_re = ws + TSZ;
    float* S_im = S_re + NBATCH * L_LEN;
    float* wts  = S_im + NBATCH * L_LEN;
    int*   shifts = (int*)(wts + NBATCH * TOPK);

    hipMemsetAsync(S_re, 0, (size_t)2 * NBATCH * L_LEN * sizeof(float), stream);

    transpose_kernel<<<dim3(L_LEN / 64, CH512 / 64, NBATCH * 2), dim3(256), 0, stream>>>(
        q, k, qT, kT);
    corr_fft_kernel<<<dim3(1024), dim3(256), 0, stream>>>(qT, kT, S_re, S_im);
    ifft_topk_kernel<<<dim3(NBATCH), dim3(256), 0, stream>>>(S_re, S_im, wts, shifts);
    agg_kernel<<<dim3(NBATCH * (CH512 / 4)), dim3(512), 0, stream>>>(v, wts, shifts, out);
}